// Round 13
// baseline (675.468 us; speedup 1.0000x reference)
//
#include <hip/hip_runtime.h>
#include <hip/hip_bf16.h>

#define N_NODES 100000
#define N_EDGES 1600000
#define N_GRAPHS 1024
#define F_NODE 16
#define F_EDGE 8
#define F_GRAPH 10
#define HD 64
#define HD2 128
#define GEN_EPS 1e-7f
#define NB1 ((N_NODES + 511) / 512)        // 196 scan blocks (512-wide)
#define DEGZ_BLK ((N_NODES + 255) / 256)   // 391 blocks worth of deg zeroing

typedef unsigned short u16;
typedef unsigned int u32;
typedef __attribute__((ext_vector_type(8))) short short8;
typedef __attribute__((ext_vector_type(4))) float floatx4;

__device__ __forceinline__ u16 f2bf(float x) {   // RNE bf16 (finite inputs)
    u32 u = __float_as_uint(x);
    return (u16)((u + 0x7FFFu + ((u >> 16) & 1u)) >> 16);
}
__device__ __forceinline__ float bf2f(u16 u) {
    return __uint_as_float(((u32)u) << 16);
}
__device__ __forceinline__ float u2f(unsigned int u) {
    return __uint_as_float(u);
}

// h[n][f] = node_b[f] + sum_k x[n][k]*node_W[k][f]; emits fp32 h + bf16 hb.
// Also absorbs the two old memsets: blocks <DEGZ_BLK zero deg, block 0
// zeroes the srcs overrun pad (stream-ordered before k_hist).
__global__ void __launch_bounds__(256) k_node_embed(
        const float* __restrict__ x, const float* __restrict__ W,
        const float* __restrict__ b, float* __restrict__ h,
        u16* __restrict__ hb, int* __restrict__ deg, int* __restrict__ srcs) {
    __shared__ float sW[F_NODE * HD];
    __shared__ float sb[HD];
    if (blockIdx.x < DEGZ_BLK) {
        int z = blockIdx.x * 256 + threadIdx.x;
        if (z < N_NODES) deg[z] = 0;
    }
    if (blockIdx.x == 0 && threadIdx.x < 64) srcs[N_EDGES + threadIdx.x] = 0;
    for (int i = threadIdx.x; i < F_NODE * HD; i += 256) sW[i] = W[i];
    if (threadIdx.x < HD) sb[threadIdx.x] = b[threadIdx.x];
    __syncthreads();
    int t = blockIdx.x * 256 + threadIdx.x;
    if (t >= N_NODES * HD) return;
    int n = t >> 6, f = t & 63;
    const float* xr = x + (size_t)n * F_NODE;
    float acc = sb[f];
#pragma unroll
    for (int k = 0; k < F_NODE; k++) acc += xr[k] * sW[k * HD + f];
    h[t] = acc;
    hb[t] = f2bf(acc);
}

// ---- CSR build ----
__global__ void __launch_bounds__(256) k_hist(
        const int* __restrict__ dst, int* __restrict__ deg,
        int* __restrict__ rank) {
    int e = blockIdx.x * 256 + threadIdx.x;
    if (e >= N_EDGES) return;
    rank[e] = atomicAdd(&deg[dst[e]], 1);
}

// 512-wide block sums (196 blocks).
__global__ void __launch_bounds__(512) k_scan1(
        const int* __restrict__ deg, int* __restrict__ bsum) {
    __shared__ int red[512];
    int t = threadIdx.x;
    int g = blockIdx.x * 512 + t;
    red[t] = (g < N_NODES) ? deg[g] : 0;
    __syncthreads();
    for (int s = 256; s > 0; s >>= 1) {
        if (t < s) red[t] += red[t + s];
        __syncthreads();
    }
    if (t == 0) bsum[blockIdx.x] = red[0];
}

// Merged scan2+scan3: every block redundantly scans bsum[0..NB1) in LDS
// (cheap: 196 ints, 9 Hillis steps), takes its exclusive block prefix, then
// does the per-element scan of its 512-node chunk. One dispatch instead of two.
__global__ void __launch_bounds__(512) k_scan23(
        const int* __restrict__ deg, const int* __restrict__ bsum,
        int* __restrict__ off) {
    __shared__ int sh[512];
    __shared__ int so[512];
    int t = threadIdx.x;
    int v = (t < NB1) ? bsum[t] : 0;
    sh[t] = v;
    so[t] = v;
    __syncthreads();
    for (int d = 1; d < 512; d <<= 1) {
        int u = (t >= d) ? sh[t - d] : 0;
        __syncthreads();
        sh[t] += u;
        __syncthreads();
    }
    int bpre = sh[blockIdx.x] - so[blockIdx.x];   // exclusive prefix of this block
    __syncthreads();                              // before reusing sh
    int g = blockIdx.x * 512 + t;
    int v2 = (g < N_NODES) ? deg[g] : 0;
    sh[t] = v2;
    __syncthreads();
    for (int d = 1; d < 512; d <<= 1) {
        int u = (t >= d) ? sh[t - d] : 0;
        __syncthreads();
        sh[t] += u;
        __syncthreads();
    }
    int incl = sh[t];
    if (g < N_NODES) off[g] = bpre + incl - v2;
    if (g == N_NODES - 1) off[N_NODES] = bpre + incl;
}

// Scatter edge attrs (verbatim r10) + separate srcs[] array.
__global__ void __launch_bounds__(256) k_scatter(
        const int* __restrict__ src, const int* __restrict__ dst,
        const int* __restrict__ rank, const int* __restrict__ off,
        const float* __restrict__ eattr,
        unsigned int* __restrict__ rec, int* __restrict__ srcs) {
    int e = blockIdx.x * 256 + threadIdx.x;
    if (e >= N_EDGES) return;
    const uint4* ap = reinterpret_cast<const uint4*>(eattr + (size_t)e * F_EDGE);
    uint4 a0 = ap[0], a1 = ap[1];           // coalesced 32B read
    int pos = off[dst[e]] + rank[e];
    uint4* op = reinterpret_cast<uint4*>(rec + (size_t)pos * 8);
    op[0] = a0;                              // one 32B sector
    op[1] = a1;
    srcs[pos] = src[e];
}

// ---- GENConv aggregation (r10 champion, byte-identical) ----
__global__ void __launch_bounds__(256) k_gen_agg(
        const float* __restrict__ h, const u16* __restrict__ hb,
        const int* __restrict__ off,
        const unsigned int* __restrict__ rec,
        const int* __restrict__ srcs,
        const float* __restrict__ eW, const float* __restrict__ eb,
        u16* __restrict__ outbb) {
    __shared__ float sAttr[4][64];          // per-wave chunk staging, 1KB
    int wid = threadIdx.x >> 6;
    int lane = threadIdx.x & 63;
    int f = lane;
    float w[F_EDGE];
#pragma unroll
    for (int k = 0; k < F_EDGE; k++) w[k] = eW[k * HD + f];
    float bfv = eb[f];
    int wave0 = blockIdx.x * 4 + wid;
    const int NW = gridDim.x * 4;
    for (int n0 = wave0; n0 < N_NODES; n0 += NW) {
        int n = __builtin_amdgcn_readfirstlane(n0);
        int beg = off[n], end = off[n + 1];
        size_t idx = (size_t)n * HD + f;
        float hroot = h[idx];                 // hoisted; overlaps edge loop
        float den = 0.f, nm = 0.f;
        if (beg < end) {
            int i = beg;
            float av = 0.f;
            if (beg + (lane >> 3) < end) av = u2f(rec[(size_t)beg * 8 + lane]);
            int s8[8];
#pragma unroll
            for (int u = 0; u < 8; u++) s8[u] = srcs[beg + u];
            while (true) {
                float hv[8];
#pragma unroll
                for (int u = 0; u < 8; u++)
                    hv[u] = bf2f(hb[(size_t)s8[u] * HD + f]);
                int inx = i + 8;
                bool more = inx < end;
                float avN = 0.f;
                int s8N[8];
                if (more) {
                    if (inx + (lane >> 3) < end)
                        avN = u2f(rec[(size_t)inx * 8 + lane]);
#pragma unroll
                    for (int u = 0; u < 8; u++) s8N[u] = srcs[inx + u];
                } else {
#pragma unroll
                    for (int u = 0; u < 8; u++) s8N[u] = 0;
                }
                sAttr[wid][lane] = av;        // same-wave stage, no barrier
#pragma unroll
                for (int u = 0; u < 8; u++) {
                    if (i + u < end) {        // uniform guard
                        const floatx4* A = reinterpret_cast<const floatx4*>(
                            &sAttr[wid][u * 8]);
                        floatx4 a0 = A[0], a1 = A[1];   // broadcast ds_read_b128
                        float ea = bfv + a0.x * w[0] + a0.y * w[1]
                                       + a0.z * w[2] + a0.w * w[3]
                                       + a1.x * w[4] + a1.y * w[5]
                                       + a1.z * w[6] + a1.w * w[7];
                        float r = fmaxf(hv[u] + ea, 0.f);
                        float ev = __expf(r);
                        den += ev;
                        nm += r * ev;
                    }
                }
                if (!more) break;
                i = inx;
                av = avN;
#pragma unroll
                for (int u = 0; u < 8; u++) s8[u] = s8N[u];
            }
        }
        float agg = (end > beg) ? (nm / fmaxf(den, 1e-16f) + GEN_EPS) : 0.f;
        outbb[idx] = f2bf(hroot + agg);
    }
}

// ---- Fused MLP (MFMA), r10 champion, byte-identical ----
__global__ void __launch_bounds__(256) k_mlp(
        const u16* __restrict__ inb,
        const float* __restrict__ W1, const float* __restrict__ b1,
        const float* __restrict__ W2, const float* __restrict__ b2,
        float* __restrict__ hout, u16* __restrict__ hbout) {
    __shared__ u16 wB1[HD2][HD + 8];    // [j][k], 18.4 KB
    __shared__ u16 wB2[HD][HD2 + 8];    // [c][j], 17.4 KB
    __shared__ u16 sHid[64][HD2 + 8];   // [local n][j], 17.4 KB
    __shared__ float sb1[HD2];
    __shared__ float sb2[HD];
    int tid = threadIdx.x;
    for (int i = tid; i < HD * HD2; i += 256) {
        int ff = i >> 7, j = i & 127;
        wB1[j][ff] = f2bf(W1[i]);
    }
    for (int i = tid; i < HD2 * HD; i += 256) {
        int j = i >> 6, c = i & 63;
        wB2[c][j] = f2bf(W2[i]);
    }
    if (tid < HD2) sb1[tid] = b1[tid];
    if (tid < HD) sb2[tid] = b2[tid];
    __syncthreads();
    int wid = tid >> 6, lane = tid & 63;
    int quad = lane >> 4, lm = lane & 15;
    int n0 = blockIdx.x * 64 + wid * 16;
    bool active = (n0 < N_NODES);         // 100000 % 16 == 0: whole-tile guard
    if (active) {
        int node = n0 + lm;
        short8 a[2];
        const u16* ar = inb + (size_t)node * HD;
#pragma unroll
        for (int kk = 0; kk < 2; kk++)
            a[kk] = *reinterpret_cast<const short8*>(ar + kk * 32 + quad * 8);
#pragma unroll
        for (int jt = 0; jt < 8; jt++) {
            int jb = jt * 16;
            float bias = sb1[jb + lm];
            floatx4 acc = {bias, bias, bias, bias};
#pragma unroll
            for (int kk = 0; kk < 2; kk++) {
                const short8* bp = reinterpret_cast<const short8*>(
                    &wB1[jb + lm][kk * 32 + quad * 8]);
                acc = __builtin_amdgcn_mfma_f32_16x16x32_bf16(a[kk], *bp, acc, 0, 0, 0);
            }
#pragma unroll
            for (int r = 0; r < 4; r++) {
                int lr = wid * 16 + quad * 4 + r;
                sHid[lr][jb + lm] = f2bf(fmaxf(acc[r], 0.f));
            }
        }
    }
    __syncthreads();
    if (active) {
        short8 a2[4];
#pragma unroll
        for (int kk = 0; kk < 4; kk++)
            a2[kk] = *reinterpret_cast<const short8*>(
                &sHid[wid * 16 + lm][kk * 32 + quad * 8]);
#pragma unroll
        for (int ct = 0; ct < 4; ct++) {
            int cb = ct * 16;
            float bias = sb2[cb + lm];
            floatx4 acc = {bias, bias, bias, bias};
#pragma unroll
            for (int kk = 0; kk < 4; kk++) {
                const short8* bp = reinterpret_cast<const short8*>(
                    &wB2[cb + lm][kk * 32 + quad * 8]);
                acc = __builtin_amdgcn_mfma_f32_16x16x32_bf16(a2[kk], *bp, acc, 0, 0, 0);
            }
#pragma unroll
            for (int r = 0; r < 4; r++) {
                int orow = n0 + quad * 4 + r;
                float o = fmaxf(acc[r], 0.f);
                hout[(size_t)orow * HD + cb + lm] = o;
                hbout[(size_t)orow * HD + cb + lm] = f2bf(o);
            }
        }
    }
}

// Fused pool+head: one 64-thread block per graph. Pool = binary-search range
// + per-f mean (coalesced fp32 rows); head = proven k_head body inline.
__global__ void __launch_bounds__(64) k_poolhead(
        const float* __restrict__ h, const int* __restrict__ batch,
        const float* __restrict__ gattr,
        const float* __restrict__ d1W, const float* __restrict__ d1b,
        const float* __restrict__ d2W, const float* __restrict__ d2b,
        const float* __restrict__ oW, const float* __restrict__ ob,
        float* __restrict__ out) {
    int g = blockIdx.x;
    int t = threadIdx.x;
    __shared__ float si[HD + F_GRAPH];
    __shared__ float s1[32], s2[32];
    // pool range
    int lo = 0, hi = N_NODES;
    while (lo < hi) {
        int mid = (lo + hi) >> 1;
        if (batch[mid] < g) lo = mid + 1; else hi = mid;
    }
    int b = lo;
    int lo2 = b, hi2 = N_NODES;
    while (lo2 < hi2) {
        int mid = (lo2 + hi2) >> 1;
        if (batch[mid] < g + 1) lo2 = mid + 1; else hi2 = mid;
    }
    int e = lo2;
    float s = 0.f;
    for (int n = b; n < e; n++) s += h[(size_t)n * HD + t];
    float cnt = fmaxf((float)(e - b), 1.f);
    si[t] = s / cnt;
    if (t < F_GRAPH) si[HD + t] = gattr[(size_t)g * F_GRAPH + t];
    __syncthreads();
    if (t < 32) {
        float acc = d1b[t];
        for (int i = 0; i < HD + F_GRAPH; i++) acc += si[i] * d1W[i * 32 + t];
        s1[t] = fmaxf(acc, 0.f);
    }
    __syncthreads();
    if (t < 32) {
        float acc = d2b[t];
        for (int i = 0; i < 32; i++) acc += s1[i] * d2W[i * 32 + t];
        s2[t] = fmaxf(acc, 0.f);
    }
    __syncthreads();
    if (t == 0) {
        float acc = ob[0];
        for (int i = 0; i < 32; i++) acc += s2[i] * oW[i];
        out[g] = 1.f / (1.f + __expf(-acc));
    }
}

extern "C" void kernel_launch(void* const* d_in, const int* in_sizes, int n_in,
                              void* d_out, int out_size, void* d_ws, size_t ws_size,
                              hipStream_t stream) {
    const float* x     = (const float*)d_in[0];
    const float* eattr = (const float*)d_in[1];
    const float* gattr = (const float*)d_in[2];
    const int*   eidx  = (const int*)d_in[3];
    const int*   batch = (const int*)d_in[4];
    const float* nodeW = (const float*)d_in[5];
    const float* nodeb = (const float*)d_in[6];
    const float* edgeW = (const float*)d_in[7];
    const float* edgeb = (const float*)d_in[8];
    const float* cW1[3] = {(const float*)d_in[9],  (const float*)d_in[13], (const float*)d_in[17]};
    const float* cb1[3] = {(const float*)d_in[10], (const float*)d_in[14], (const float*)d_in[18]};
    const float* cW2[3] = {(const float*)d_in[11], (const float*)d_in[15], (const float*)d_in[19]};
    const float* cb2[3] = {(const float*)d_in[12], (const float*)d_in[16], (const float*)d_in[20]};
    const float* d1W = (const float*)d_in[21];
    const float* d1b = (const float*)d_in[22];
    const float* d2W = (const float*)d_in[23];
    const float* d2b = (const float*)d_in[24];
    const float* oW  = (const float*)d_in[25];
    const float* ob  = (const float*)d_in[26];

    const int* src = eidx;
    const int* dst = eidx + N_EDGES;

    // workspace layout (r10 champion; bpre/pooled dropped)
    char* p = (char*)d_ws;
    float* h      = (float*)p; p += (size_t)N_NODES * HD * 4;       // 25.6 MB
    u16*   outbb  = (u16*)p;   p += (size_t)N_NODES * HD * 2;       // 12.8 MB
    int*   srcs   = (int*)p;   p += (size_t)(N_EDGES + 64) * 4;     // 6.4 MB + pad
    unsigned int* rec = (unsigned int*)p; p += (size_t)(N_EDGES + 8) * F_EDGE * 4; // 51.2 MB + pad
    u16*   hb     = (u16*)p;   p += (size_t)N_NODES * HD * 2;       // 12.8 MB
    int*   off    = (int*)p;   p += (size_t)(N_NODES + 1) * 4;
    int*   deg    = (int*)p;   p += (size_t)N_NODES * 4;
    int*   rank   = (int*)p;   p += (size_t)N_EDGES * 4;            // 6.4 MB
    int*   bsum   = (int*)p;   p += (size_t)(NB1 + 1) * 4;

    const int EB = (N_EDGES + 255) / 256;
    const int NBM = (N_NODES + 63) / 64;   // 1563 MFMA blocks (64 nodes each)

    // embed also zeroes deg + srcs pad (replaces 2 memset dispatches)
    k_node_embed<<<(N_NODES * HD + 255) / 256, 256, 0, stream>>>(
        x, nodeW, nodeb, h, hb, deg, srcs);
    k_hist<<<EB, 256, 0, stream>>>(dst, deg, rank);
    k_scan1<<<NB1, 512, 0, stream>>>(deg, bsum);
    k_scan23<<<NB1, 512, 0, stream>>>(deg, bsum, off);
    k_scatter<<<EB, 256, 0, stream>>>(src, dst, rank, off, eattr, rec, srcs);

    for (int l = 0; l < 3; l++) {
        k_gen_agg<<<2048, 256, 0, stream>>>(
            h, hb, off, rec, srcs, edgeW, edgeb, outbb);
        k_mlp<<<NBM, 256, 0, stream>>>(outbb, cW1[l], cb1[l], cW2[l], cb2[l], h, hb);
    }

    k_poolhead<<<N_GRAPHS, 64, 0, stream>>>(h, batch, gattr,
                                            d1W, d1b, d2W, d2b, oW, ob,
                                            (float*)d_out);
}